// Round 8
// baseline (222.828 us; speedup 1.0000x reference)
//
#include <hip/hip_runtime.h>
#include <hip/hip_bf16.h>

// B=4, S=1024, E=1024, H=16, d=64 -> NH=64 heads. Out: [64,1024,1024] fp32.
// sparsemax(Q K^T) per head, SCALE=1.0. V chunk of the projection is dead.

typedef __attribute__((ext_vector_type(8))) short bf16x8;   // 8 bf16 = 4 VGPRs
typedef __attribute__((ext_vector_type(4))) float f32x4;

__device__ __forceinline__ ushort f2bf(float x) {           // RNE f32 -> bf16 bits
    uint u = __float_as_uint(x);
    u += 0x7FFFu + ((u >> 16) & 1u);
    return (ushort)(u >> 16);
}
__device__ __forceinline__ float bf2f(ushort h) {
    return __uint_as_float(((uint)h) << 16);
}

typedef const __attribute__((address_space(1))) unsigned int* gptr_t;
typedef __attribute__((address_space(3))) unsigned int* sptr_t;
__device__ __forceinline__ void gload_lds16(const void* g, void* l) {
    __builtin_amdgcn_global_load_lds((gptr_t)g, (sptr_t)l, 16, 0, 0);
}

// ---- 16-lane-group reductions on the VALU pipe (4 DPP hops, no DS ops) ----
// xor1 (quad_perm 0xB1), xor2 (quad_perm 0x4E), row_ror:4 (0x124),
// row_ror:8 (0x128): every lane ends with its 16-lane group's total.
// (These DPP encodings are HW-validated by rounds 6-7 passing the bench.)
__device__ __forceinline__ float grp16_sum(float v) {
    v += __int_as_float(__builtin_amdgcn_update_dpp(0, __float_as_int(v), 0xB1, 0xF, 0xF, true));
    v += __int_as_float(__builtin_amdgcn_update_dpp(0, __float_as_int(v), 0x4E, 0xF, 0xF, true));
    v += __int_as_float(__builtin_amdgcn_update_dpp(0, __float_as_int(v), 0x124, 0xF, 0xF, true));
    v += __int_as_float(__builtin_amdgcn_update_dpp(0, __float_as_int(v), 0x128, 0xF, 0xF, true));
    return v;
}
__device__ __forceinline__ float grp16_max(float v) {
    v = fmaxf(v, __int_as_float(__builtin_amdgcn_update_dpp(0, __float_as_int(v), 0xB1, 0xF, 0xF, true)));
    v = fmaxf(v, __int_as_float(__builtin_amdgcn_update_dpp(0, __float_as_int(v), 0x4E, 0xF, 0xF, true)));
    v = fmaxf(v, __int_as_float(__builtin_amdgcn_update_dpp(0, __float_as_int(v), 0x124, 0xF, 0xF, true)));
    v = fmaxf(v, __int_as_float(__builtin_amdgcn_update_dpp(0, __float_as_int(v), 0x128, 0xF, 0xF, true)));
    return v;
}

// ---------------------------------------------------------------------------
// Kernel 0: fp32 -> split bf16 (hi = bf16(v), lo = bf16(v - hi)), elementwise.
// ---------------------------------------------------------------------------
__global__ __launch_bounds__(256)
void convert_split_kernel(const float* __restrict__ in, ushort* __restrict__ hi,
                          ushort* __restrict__ lo, int n4)
{
    int i = blockIdx.x * 256 + threadIdx.x;
    const int stride = gridDim.x * 256;
    for (; i < n4; i += stride) {
        float4 v = ((const float4*)in)[i];
        ushort4 h, l;
        h.x = f2bf(v.x); l.x = f2bf(v.x - bf2f(h.x));
        h.y = f2bf(v.y); l.y = f2bf(v.y - bf2f(h.y));
        h.z = f2bf(v.z); l.z = f2bf(v.z - bf2f(h.z));
        h.w = f2bf(v.w); l.w = f2bf(v.w - bf2f(h.w));
        ((ushort4*)hi)[i] = h;
        ((ushort4*)lo)[i] = l;
    }
}

// ---------------------------------------------------------------------------
// Kernel 1: projection GEMM via split-bf16 MFMA (unchanged from round 3).
// ---------------------------------------------------------------------------
__global__ __launch_bounds__(512)
void proj_kernel(const ushort* __restrict__ xh, const ushort* __restrict__ xl,
                 const ushort* __restrict__ wh, const ushort* __restrict__ wl,
                 ushort* __restrict__ khi, ushort* __restrict__ klo,
                 ushort* __restrict__ qhi, ushort* __restrict__ qlo)
{
    __shared__ __align__(16) ushort Ah[128 * 64], Al[128 * 64];   // 16 KB each
    __shared__ __align__(16) ushort Bh[128 * 64], Bl[128 * 64];   // total 64 KB
    const int tid = threadIdx.x, w = tid >> 6, l = tid & 63;
    const int m0 = blockIdx.y * 128, c0 = blockIdx.x * 128;
    const int wr = w >> 2, wc = w & 3;          // wave -> 64m x 32c sub-tile
    const int lm = l & 15, lk = l >> 4;
    const int sslot = (l & 7) ^ (l >> 3);       // pre-swizzled source chunk

    f32x4 acc[4][2];
#pragma unroll
    for (int mf = 0; mf < 4; ++mf)
#pragma unroll
        for (int nf = 0; nf < 2; ++nf) acc[mf][nf] = (f32x4){0.f, 0.f, 0.f, 0.f};

    for (int k0 = 0; k0 < 1024; k0 += 64) {
        __syncthreads();                        // prev ds_reads done
#pragma unroll
        for (int i = 0; i < 2; ++i) {
            const int r = 16 * w + 8 * i + (l >> 3);
            const size_t ga = (size_t)(m0 + r) * 1024 + k0 + sslot * 8;
            const size_t gb = (size_t)(c0 + r) * 1024 + k0 + sslot * 8;
            const int lb = (16 * w + 8 * i) * 128;          // LDS byte base (uniform)
            gload_lds16(xh + ga, (char*)Ah + lb);
            gload_lds16(xl + ga, (char*)Al + lb);
            gload_lds16(wh + gb, (char*)Bh + lb);
            gload_lds16(wl + gb, (char*)Bl + lb);
        }
        __syncthreads();                        // vmcnt drained by barrier
#pragma unroll
        for (int kc = 0; kc < 2; ++kc) {
            bf16x8 a_h[4], a_l[4], b_h[2], b_l[2];
#pragma unroll
            for (int mf = 0; mf < 4; ++mf) {
                const int ra = wr * 64 + mf * 16 + lm;
                const int off = ra * 128 + ((kc * 4 + lk) ^ (ra & 7)) * 16;
                a_h[mf] = *(const bf16x8*)((const char*)Ah + off);
                a_l[mf] = *(const bf16x8*)((const char*)Al + off);
            }
#pragma unroll
            for (int nf = 0; nf < 2; ++nf) {
                const int rb = wc * 32 + nf * 16 + lm;
                const int off = rb * 128 + ((kc * 4 + lk) ^ (rb & 7)) * 16;
                b_h[nf] = *(const bf16x8*)((const char*)Bh + off);
                b_l[nf] = *(const bf16x8*)((const char*)Bl + off);
            }
#pragma unroll
            for (int mf = 0; mf < 4; ++mf)
#pragma unroll
                for (int nf = 0; nf < 2; ++nf) {
                    f32x4 a = acc[mf][nf];
                    a = __builtin_amdgcn_mfma_f32_16x16x32_bf16(a_h[mf], b_h[nf], a, 0, 0, 0);
                    a = __builtin_amdgcn_mfma_f32_16x16x32_bf16(a_l[mf], b_h[nf], a, 0, 0, 0);
                    a = __builtin_amdgcn_mfma_f32_16x16x32_bf16(a_h[mf], b_l[nf], a, 0, 0, 0);
                    acc[mf][nf] = a;
                }
        }
    }

    // epilogue: split-bf16, scatter to head-major K / Q buffers
#pragma unroll
    for (int mf = 0; mf < 4; ++mf)
#pragma unroll
        for (int nf = 0; nf < 2; ++nf) {
            const int c = c0 + wc * 32 + nf * 16 + lm;
            const int cc = c & 1023;
            ushort* dh = (c < 1024) ? khi : qhi;
            ushort* dl = (c < 1024) ? klo : qlo;
#pragma unroll
            for (int rg = 0; rg < 4; ++rg) {
                const int m = m0 + wr * 64 + mf * 16 + lk * 4 + rg;
                const float v = acc[mf][nf][rg];
                const ushort h = f2bf(v), lo_ = f2bf(v - bf2f(h));
                const int nhd = ((m >> 10) << 4) + (cc >> 6);
                const size_t off = ((size_t)nhd << 16) + ((size_t)(m & 1023) << 6) + (cc & 63);
                dh[off] = h;
                dl[off] = lo_;
            }
        }
}

// ---------------------------------------------------------------------------
// Kernel 2: fused logits MFMA-GEMM + REGISTER-RESIDENT sparsemax (round 8).
// 512 threads = 8 waves, 16 q-rows/block; wave wv holds its 16x128 strip in
// acc[8] (lane: rows lk*4+rg, cols wv*128 + nf*16 + lm — HW-verified layout).
// NO logits LDS (was 64 KB -> serial phase pipeline at 2 blocks/CU). Instead:
//   scan in-lane (8 vals/row) -> 4-hop DPP 16-lane reduce -> 2 KB ping-pong
//   partials LDS -> barrier -> in-lane combine of 8 wave-partials.
// All waves derive identical taus from shared partials -> uniform loop exit.
// LDS 2 KB + launch_bounds(512,8) (<=64 VGPR) -> 4 blocks/CU: the L2-read /
// VALU / HBM-write phases of different blocks finally overlap.
// Kept: XCD-chunked swizzle, tau0 = rowmax-1 Michelot, NT stores.
// ---------------------------------------------------------------------------
__global__ __launch_bounds__(512, 8)
void attn_sparsemax_kernel(const ushort* __restrict__ khi, const ushort* __restrict__ klo,
                           const ushort* __restrict__ qhi, const ushort* __restrict__ qlo,
                           float* __restrict__ out)
{
    __shared__ __align__(16) float psum[2][8][16];   // [buf][wave][row]
    __shared__ __align__(16) float pcnt[2][8][16];   // counts kept as float (exact)
    const int tid = threadIdx.x, wv = tid >> 6, ln = tid & 63;
    const int bid = blockIdx.x;
    const int vb  = (bid & 7) * 512 + (bid >> 3);    // XCD-chunked remap (4096=8*512)
    const int n   = vb >> 6;                         // head 0..63
    const int r0  = (vb & 63) << 4;                  // q-row base
    const size_t hb = (size_t)n << 16;               // head base, elems
    const int lm = ln & 15, lk = ln >> 4;

    // A fragments: Q rows r0 + lm, d = kc*32 + lk*8 + j (16B/lane)
    bf16x8 qh[2], ql[2];
#pragma unroll
    for (int kc = 0; kc < 2; ++kc) {
        const size_t o = hb + ((size_t)(r0 + lm) << 6) + kc * 32 + lk * 8;
        qh[kc] = *(const bf16x8*)(qhi + o);
        ql[kc] = *(const bf16x8*)(qlo + o);
    }

    f32x4 acc[8];
#pragma unroll
    for (int nf = 0; nf < 8; ++nf) acc[nf] = (f32x4){0.f, 0.f, 0.f, 0.f};

    const int c0 = wv * 128;                         // this wave's 128-col strip
#pragma unroll
    for (int nf = 0; nf < 8; ++nf) {
        const size_t o = hb + ((size_t)(c0 + nf * 16 + lm) << 6) + lk * 8;
        bf16x8 bh0 = *(const bf16x8*)(khi + o);
        bf16x8 bh1 = *(const bf16x8*)(khi + o + 32);
        bf16x8 bl0 = *(const bf16x8*)(klo + o);
        bf16x8 bl1 = *(const bf16x8*)(klo + o + 32);
        f32x4 a = acc[nf];
        a = __builtin_amdgcn_mfma_f32_16x16x32_bf16(qh[0], bh0, a, 0, 0, 0);
        a = __builtin_amdgcn_mfma_f32_16x16x32_bf16(qh[1], bh1, a, 0, 0, 0);
        a = __builtin_amdgcn_mfma_f32_16x16x32_bf16(ql[0], bh0, a, 0, 0, 0);
        a = __builtin_amdgcn_mfma_f32_16x16x32_bf16(ql[1], bh1, a, 0, 0, 0);
        a = __builtin_amdgcn_mfma_f32_16x16x32_bf16(qh[0], bl0, a, 0, 0, 0);
        a = __builtin_amdgcn_mfma_f32_16x16x32_bf16(qh[1], bl1, a, 0, 0, 0);
        acc[nf] = a;
    }

    // ---- row maxes: in-lane over 8 cols, DPP over 16-lane group, LDS over waves
    {
        float pm[4];
#pragma unroll
        for (int rg = 0; rg < 4; ++rg) {
            float m = acc[0][rg];
#pragma unroll
            for (int nf = 1; nf < 8; ++nf) m = fmaxf(m, acc[nf][rg]);
            pm[rg] = grp16_max(m);
        }
        if (lm == 0)
            *(f32x4*)&psum[0][wv][lk * 4] = (f32x4){pm[0], pm[1], pm[2], pm[3]};
    }
    __syncthreads();

    float tau[4], kold[4];
    {
        f32x4 MX = *(const f32x4*)&psum[0][0][lk * 4];
#pragma unroll
        for (int w2 = 1; w2 < 8; ++w2) {
            f32x4 v = *(const f32x4*)&psum[0][w2][lk * 4];
            MX[0] = fmaxf(MX[0], v[0]); MX[1] = fmaxf(MX[1], v[1]);
            MX[2] = fmaxf(MX[2], v[2]); MX[3] = fmaxf(MX[3], v[3]);
        }
#pragma unroll
        for (int rg = 0; rg < 4; ++rg) { tau[rg] = MX[rg] - 1.0f; kold[rg] = 0.f; }
    }

    // ---- Michelot from tau0 = rowmax-1 (support tiny; ~2-3 passes) ----
    int buf = 1;
    for (int it = 0; it < 32; ++it) {
        float s[4], c[4];
#pragma unroll
        for (int rg = 0; rg < 4; ++rg) {
            float sv = 0.f, cv = 0.f;
#pragma unroll
            for (int nf = 0; nf < 8; ++nf) {
                const bool p = acc[nf][rg] > tau[rg];
                sv += p ? acc[nf][rg] : 0.f;
                cv += p ? 1.f : 0.f;
            }
            s[rg] = grp16_sum(sv);
            c[rg] = grp16_sum(cv);
        }
        if (lm == 0) {
            *(f32x4*)&psum[buf][wv][lk * 4] = (f32x4){s[0], s[1], s[2], s[3]};
            *(f32x4*)&pcnt[buf][wv][lk * 4] = (f32x4){c[0], c[1], c[2], c[3]};
        }
        __syncthreads();
        f32x4 S = (f32x4){0.f, 0.f, 0.f, 0.f}, C = (f32x4){0.f, 0.f, 0.f, 0.f};
#pragma unroll
        for (int w2 = 0; w2 < 8; ++w2) {
            S += *(const f32x4*)&psum[buf][w2][lk * 4];
            C += *(const f32x4*)&pcnt[buf][w2][lk * 4];
        }
        bool st = true;
#pragma unroll
        for (int rg = 0; rg < 4; ++rg) {
            st = st && (C[rg] == kold[rg]);
            kold[rg] = C[rg];
            tau[rg] = (S[rg] - 1.0f) / C[rg];   // no-op when row already converged
        }
        buf ^= 1;
        if (__all(st)) break;    // identical totals in every wave -> uniform exit
    }

    // ---- fused relu write straight from registers ----
    const size_t rowbase = ((size_t)n << 10) + r0;
#pragma unroll
    for (int nf = 0; nf < 8; ++nf) {
#pragma unroll
        for (int rg = 0; rg < 4; ++rg) {
            const size_t off = ((rowbase + lk * 4 + rg) << 10) + c0 + nf * 16 + lm;
            __builtin_nontemporal_store(fmaxf(acc[nf][rg] - tau[rg], 0.f), out + off);
        }
    }
}

// ---------------------------------------------------------------------------
extern "C" void kernel_launch(void* const* d_in, const int* in_sizes, int n_in,
                              void* d_out, int out_size, void* d_ws, size_t ws_size,
                              hipStream_t stream) {
    const float* x = (const float*)d_in[0];          // [4096, 1024]
    const float* w = (const float*)d_in[1];          // [3072, 1024]
    float* out = (float*)d_out;                      // [64, 1024, 1024]

    const size_t HE = (size_t)64 * 1024 * 64;        // 4.19M elems per head buf
    const size_t XE = (size_t)4096 * 1024;           // x elems
    const size_t WE = (size_t)2048 * 1024;           // W' elems (rows 1024..3071)
    ushort* khi = (ushort*)d_ws;
    ushort* klo = khi + HE;
    ushort* qhi = klo + HE;
    ushort* qlo = qhi + HE;
    ushort* xh  = qlo + HE;
    ushort* xl  = xh + XE;
    ushort* wh  = xl + XE;
    ushort* wl  = wh + WE;                           // total ~58.7 MB of d_ws

    convert_split_kernel<<<2048, 256, 0, stream>>>(x, xh, xl, (int)(XE / 4));
    convert_split_kernel<<<2048, 256, 0, stream>>>(w + (size_t)1024 * 1024, wh, wl, (int)(WE / 4));
    proj_kernel<<<dim3(16, 32), 512, 0, stream>>>(xh, xl, wh, wl, khi, klo, qhi, qlo);
    attn_sparsemax_kernel<<<4096, 512, 0, stream>>>(khi, klo, qhi, qlo, out);
}

// Round 9
// 219.399 us; speedup vs baseline: 1.0156x; 1.0156x over previous
//
#include <hip/hip_runtime.h>
#include <hip/hip_bf16.h>

// B=4, S=1024, E=1024, H=16, d=64 -> NH=64 heads. Out: [64,1024,1024] fp32.
// sparsemax(Q K^T) per head, SCALE=1.0. V chunk of the projection is dead.

typedef __attribute__((ext_vector_type(8))) short bf16x8;   // 8 bf16 = 4 VGPRs
typedef __attribute__((ext_vector_type(4))) float f32x4;

__device__ __forceinline__ ushort f2bf(float x) {           // RNE f32 -> bf16 bits
    uint u = __float_as_uint(x);
    u += 0x7FFFu + ((u >> 16) & 1u);
    return (ushort)(u >> 16);
}
__device__ __forceinline__ float bf2f(ushort h) {
    return __uint_as_float(((uint)h) << 16);
}

typedef const __attribute__((address_space(1))) unsigned int* gptr_t;
typedef __attribute__((address_space(3))) unsigned int* sptr_t;
__device__ __forceinline__ void gload_lds16(const void* g, void* l) {
    __builtin_amdgcn_global_load_lds((gptr_t)g, (sptr_t)l, 16, 0, 0);
}

// ---------------------------------------------------------------------------
// Kernel 0: fp32 -> split bf16 (hi = bf16(v), lo = bf16(v - hi)), elementwise.
// ---------------------------------------------------------------------------
__global__ __launch_bounds__(256)
void convert_split_kernel(const float* __restrict__ in, ushort* __restrict__ hi,
                          ushort* __restrict__ lo, int n4)
{
    int i = blockIdx.x * 256 + threadIdx.x;
    const int stride = gridDim.x * 256;
    for (; i < n4; i += stride) {
        float4 v = ((const float4*)in)[i];
        ushort4 h, l;
        h.x = f2bf(v.x); l.x = f2bf(v.x - bf2f(h.x));
        h.y = f2bf(v.y); l.y = f2bf(v.y - bf2f(h.y));
        h.z = f2bf(v.z); l.z = f2bf(v.z - bf2f(h.z));
        h.w = f2bf(v.w); l.w = f2bf(v.w - bf2f(h.w));
        ((ushort4*)hi)[i] = h;
        ((ushort4*)lo)[i] = l;
    }
}

// ---------------------------------------------------------------------------
// Kernel 1: projection GEMM via split-bf16 MFMA (unchanged from round 3).
// ---------------------------------------------------------------------------
__global__ __launch_bounds__(512)
void proj_kernel(const ushort* __restrict__ xh, const ushort* __restrict__ xl,
                 const ushort* __restrict__ wh, const ushort* __restrict__ wl,
                 ushort* __restrict__ khi, ushort* __restrict__ klo,
                 ushort* __restrict__ qhi, ushort* __restrict__ qlo)
{
    __shared__ __align__(16) ushort Ah[128 * 64], Al[128 * 64];   // 16 KB each
    __shared__ __align__(16) ushort Bh[128 * 64], Bl[128 * 64];   // total 64 KB
    const int tid = threadIdx.x, w = tid >> 6, l = tid & 63;
    const int m0 = blockIdx.y * 128, c0 = blockIdx.x * 128;
    const int wr = w >> 2, wc = w & 3;          // wave -> 64m x 32c sub-tile
    const int lm = l & 15, lk = l >> 4;
    const int sslot = (l & 7) ^ (l >> 3);       // pre-swizzled source chunk

    f32x4 acc[4][2];
#pragma unroll
    for (int mf = 0; mf < 4; ++mf)
#pragma unroll
        for (int nf = 0; nf < 2; ++nf) acc[mf][nf] = (f32x4){0.f, 0.f, 0.f, 0.f};

    for (int k0 = 0; k0 < 1024; k0 += 64) {
        __syncthreads();                        // prev ds_reads done
#pragma unroll
        for (int i = 0; i < 2; ++i) {
            const int r = 16 * w + 8 * i + (l >> 3);
            const size_t ga = (size_t)(m0 + r) * 1024 + k0 + sslot * 8;
            const size_t gb = (size_t)(c0 + r) * 1024 + k0 + sslot * 8;
            const int lb = (16 * w + 8 * i) * 128;          // LDS byte base (uniform)
            gload_lds16(xh + ga, (char*)Ah + lb);
            gload_lds16(xl + ga, (char*)Al + lb);
            gload_lds16(wh + gb, (char*)Bh + lb);
            gload_lds16(wl + gb, (char*)Bl + lb);
        }
        __syncthreads();                        // vmcnt drained by barrier
#pragma unroll
        for (int kc = 0; kc < 2; ++kc) {
            bf16x8 a_h[4], a_l[4], b_h[2], b_l[2];
#pragma unroll
            for (int mf = 0; mf < 4; ++mf) {
                const int ra = wr * 64 + mf * 16 + lm;
                const int off = ra * 128 + ((kc * 4 + lk) ^ (ra & 7)) * 16;
                a_h[mf] = *(const bf16x8*)((const char*)Ah + off);
                a_l[mf] = *(const bf16x8*)((const char*)Al + off);
            }
#pragma unroll
            for (int nf = 0; nf < 2; ++nf) {
                const int rb = wc * 32 + nf * 16 + lm;
                const int off = rb * 128 + ((kc * 4 + lk) ^ (rb & 7)) * 16;
                b_h[nf] = *(const bf16x8*)((const char*)Bh + off);
                b_l[nf] = *(const bf16x8*)((const char*)Bl + off);
            }
#pragma unroll
            for (int mf = 0; mf < 4; ++mf)
#pragma unroll
                for (int nf = 0; nf < 2; ++nf) {
                    f32x4 a = acc[mf][nf];
                    a = __builtin_amdgcn_mfma_f32_16x16x32_bf16(a_h[mf], b_h[nf], a, 0, 0, 0);
                    a = __builtin_amdgcn_mfma_f32_16x16x32_bf16(a_l[mf], b_h[nf], a, 0, 0, 0);
                    a = __builtin_amdgcn_mfma_f32_16x16x32_bf16(a_h[mf], b_l[nf], a, 0, 0, 0);
                    acc[mf][nf] = a;
                }
        }
    }

    // epilogue: split-bf16, scatter to head-major K / Q buffers
#pragma unroll
    for (int mf = 0; mf < 4; ++mf)
#pragma unroll
        for (int nf = 0; nf < 2; ++nf) {
            const int c = c0 + wc * 32 + nf * 16 + lm;
            const int cc = c & 1023;
            ushort* dh = (c < 1024) ? khi : qhi;
            ushort* dl = (c < 1024) ? klo : qlo;
#pragma unroll
            for (int rg = 0; rg < 4; ++rg) {
                const int m = m0 + wr * 64 + mf * 16 + lk * 4 + rg;
                const float v = acc[mf][nf][rg];
                const ushort h = f2bf(v), lo_ = f2bf(v - bf2f(h));
                const int nhd = ((m >> 10) << 4) + (cc >> 6);
                const size_t off = ((size_t)nhd << 16) + ((size_t)(m & 1023) << 6) + (cc & 63);
                dh[off] = h;
                dl[off] = lo_;
            }
        }
}

// ---------------------------------------------------------------------------
// Kernel 2 (round 9): SWAPPED-OPERAND fused logits MFMA + register sparsemax.
// 512 threads = 8 waves, 16 q-rows/block, 4096 blocks, XCD-chunked swizzle.
// D = mfma(A=K_frag, B=Q_frag): HW-verified C/D map (row=A-idx=(lk*4+reg),
// col=B-idx=lm) means lane lm owns q-row lm with 4 CONSECUTIVE k-cols per
// accumulator quad: acc[nf][rg] = logits[q=lm][k=c0+nf*16+lk*4+rg].
//   - output write = native float4/accumulator, plain cached stores (L2
//     write-back merges 64B segments -> no NT partial-line amplification)
//   - row reduce = 32 in-lane values + 2-hop __shfl_xor(16,32) over the 4
//     lanes sharing the row + 2.5 KB ping-pong LDS across 8 waves
// Kept: tau0 = rowmax-1 Michelot, uniform exit, XCD swizzle.
// ---------------------------------------------------------------------------
__global__ __launch_bounds__(512, 6)
void attn_sparsemax_kernel(const ushort* __restrict__ khi, const ushort* __restrict__ klo,
                           const ushort* __restrict__ qhi, const ushort* __restrict__ qlo,
                           float* __restrict__ out)
{
    __shared__ __align__(16) float pm[16][8];        // [row][wave] maxes
    __shared__ __align__(16) float ps[2][16][8];     // ping-pong sums
    __shared__ __align__(16) float pc[2][16][8];     // ping-pong counts
    const int tid = threadIdx.x, wv = tid >> 6, ln = tid & 63;
    const int bid = blockIdx.x;
    const int vb  = (bid & 7) * 512 + (bid >> 3);    // XCD-chunked remap
    const int n   = vb >> 6;                         // head 0..63
    const int r0  = (vb & 63) << 4;                  // q-row base
    const size_t hb = (size_t)n << 16;               // head base, elems
    const int lm = ln & 15, lk = ln >> 4;

    // B fragments: Q rows r0 + lm, d-slice kc*32 + lk*8 (16B/lane)
    bf16x8 qh[2], ql[2];
#pragma unroll
    for (int kc = 0; kc < 2; ++kc) {
        const size_t o = hb + ((size_t)(r0 + lm) << 6) + kc * 32 + lk * 8;
        qh[kc] = *(const bf16x8*)(qhi + o);
        ql[kc] = *(const bf16x8*)(qlo + o);
    }

    f32x4 acc[8];
#pragma unroll
    for (int nf = 0; nf < 8; ++nf) acc[nf] = (f32x4){0.f, 0.f, 0.f, 0.f};

    const int c0 = wv * 128;                         // this wave's 128 k-cols
    const ushort* Kh = khi + hb + (((size_t)(c0 + lm)) << 6) + lk * 8;
    const ushort* Kl = klo + hb + (((size_t)(c0 + lm)) << 6) + lk * 8;

#pragma unroll
    for (int nf = 0; nf < 8; ++nf) {
        const ushort* ph = Kh + (nf << 10);
        const ushort* pl = Kl + (nf << 10);
        bf16x8 kh0 = *(const bf16x8*)(ph);
        bf16x8 kh1 = *(const bf16x8*)(ph + 32);
        bf16x8 kl0 = *(const bf16x8*)(pl);
        bf16x8 kl1 = *(const bf16x8*)(pl + 32);
        f32x4 a = acc[nf];
        a = __builtin_amdgcn_mfma_f32_16x16x32_bf16(kh0, qh[0], a, 0, 0, 0);
        a = __builtin_amdgcn_mfma_f32_16x16x32_bf16(kh1, qh[1], a, 0, 0, 0);
        a = __builtin_amdgcn_mfma_f32_16x16x32_bf16(kl0, qh[0], a, 0, 0, 0);
        a = __builtin_amdgcn_mfma_f32_16x16x32_bf16(kl1, qh[1], a, 0, 0, 0);
        a = __builtin_amdgcn_mfma_f32_16x16x32_bf16(kh0, ql[0], a, 0, 0, 0);
        a = __builtin_amdgcn_mfma_f32_16x16x32_bf16(kh1, ql[1], a, 0, 0, 0);
        acc[nf] = a;
    }

    // ---- row max: 32 in-lane, 2 shfl hops, cross-wave via pm ----
    {
        float m = acc[0][0];
#pragma unroll
        for (int nf = 0; nf < 8; ++nf)
#pragma unroll
            for (int rg = 0; rg < 4; ++rg) m = fmaxf(m, acc[nf][rg]);
        m = fmaxf(m, __shfl_xor(m, 16));
        m = fmaxf(m, __shfl_xor(m, 32));
        if (ln < 16) pm[ln][wv] = m;
    }
    __syncthreads();

    float tau, kold = 0.f;
    {
        f32x4 a0 = *(const f32x4*)&pm[lm][0];
        f32x4 a1 = *(const f32x4*)&pm[lm][4];
        float mx = fmaxf(fmaxf(fmaxf(a0[0], a0[1]), fmaxf(a0[2], a0[3])),
                         fmaxf(fmaxf(a1[0], a1[1]), fmaxf(a1[2], a1[3])));
        tau = mx - 1.0f;
    }

    // ---- Michelot from tau0 = rowmax-1 (support tiny; ~2-3 passes) ----
    int buf = 0;
    for (int it = 0; it < 32; ++it) {
        float sv = 0.f, cv = 0.f;
#pragma unroll
        for (int nf = 0; nf < 8; ++nf)
#pragma unroll
            for (int rg = 0; rg < 4; ++rg) {
                const bool p = acc[nf][rg] > tau;
                sv += p ? acc[nf][rg] : 0.f;
                cv += p ? 1.f : 0.f;
            }
        sv += __shfl_xor(sv, 16); cv += __shfl_xor(cv, 16);
        sv += __shfl_xor(sv, 32); cv += __shfl_xor(cv, 32);
        if (ln < 16) { ps[buf][ln][wv] = sv; pc[buf][ln][wv] = cv; }
        __syncthreads();
        f32x4 s0 = *(const f32x4*)&ps[buf][lm][0];
        f32x4 s1 = *(const f32x4*)&ps[buf][lm][4];
        f32x4 c0v = *(const f32x4*)&pc[buf][lm][0];
        f32x4 c1v = *(const f32x4*)&pc[buf][lm][4];
        const float S = (s0[0] + s0[1]) + (s0[2] + s0[3])
                      + (s1[0] + s1[1]) + (s1[2] + s1[3]);
        const float C = (c0v[0] + c0v[1]) + (c0v[2] + c0v[3])
                      + (c1v[0] + c1v[1]) + (c1v[2] + c1v[3]);
        const bool st = (C == kold);
        kold = C;
        tau = (S - 1.0f) / C;      // bit-identical when row converged
        buf ^= 1;
        if (__all(st)) break;      // identical totals everywhere -> uniform exit
    }

    // ---- fused relu write: native float4 per accumulator, cached stores ----
    float* orow = out + ((((size_t)n << 10) + r0 + lm) << 10) + c0 + (lk << 2);
#pragma unroll
    for (int nf = 0; nf < 8; ++nf) {
        f32x4 o;
        o[0] = fmaxf(acc[nf][0] - tau, 0.f);
        o[1] = fmaxf(acc[nf][1] - tau, 0.f);
        o[2] = fmaxf(acc[nf][2] - tau, 0.f);
        o[3] = fmaxf(acc[nf][3] - tau, 0.f);
        *(f32x4*)(orow + nf * 16) = o;
    }
}

// ---------------------------------------------------------------------------
extern "C" void kernel_launch(void* const* d_in, const int* in_sizes, int n_in,
                              void* d_out, int out_size, void* d_ws, size_t ws_size,
                              hipStream_t stream) {
    const float* x = (const float*)d_in[0];          // [4096, 1024]
    const float* w = (const float*)d_in[1];          // [3072, 1024]
    float* out = (float*)d_out;                      // [64, 1024, 1024]

    const size_t HE = (size_t)64 * 1024 * 64;        // 4.19M elems per head buf
    const size_t XE = (size_t)4096 * 1024;           // x elems
    const size_t WE = (size_t)2048 * 1024;           // W' elems (rows 1024..3071)
    ushort* khi = (ushort*)d_ws;
    ushort* klo = khi + HE;
    ushort* qhi = klo + HE;
    ushort* qlo = qhi + HE;
    ushort* xh  = qlo + HE;
    ushort* xl  = xh + XE;
    ushort* wh  = xl + XE;
    ushort* wl  = wh + WE;                           // total ~58.7 MB of d_ws

    convert_split_kernel<<<2048, 256, 0, stream>>>(x, xh, xl, (int)(XE / 4));
    convert_split_kernel<<<2048, 256, 0, stream>>>(w + (size_t)1024 * 1024, wh, wl, (int)(WE / 4));
    proj_kernel<<<dim3(16, 32), 512, 0, stream>>>(xh, xl, wh, wl, khi, klo, qhi, qlo);
    attn_sparsemax_kernel<<<4096, 512, 0, stream>>>(khi, klo, qhi, qlo, out);
}

// Round 10
// 149.171 us; speedup vs baseline: 1.4938x; 1.4708x over previous
//
#include <hip/hip_runtime.h>
#include <hip/hip_bf16.h>

// B=4, S=1024, E=1024, H=16, d=64 -> NH=64 heads. Out: [64,1024,1024] fp32.
// sparsemax(Q K^T) per head, SCALE=1.0. V chunk of the projection is dead.
//
// Round-10 core change: FRAGMENT-MAJOR workspace layout for K/Q hi/lo.
// Chunk = (head n, 16-row/col block blk16, kc in {0,1}): 512 bf16 = 1 KB.
// Lane ln of a wave reads elements [ln*8, ln*8+8) of its chunk -> every MFMA
// fragment load is 1 KB CONTIGUOUS (was 64-line stride-128B gather, which
// serialized the TA unit and pinned all round-2..9 kernels at ~165 us).
// Element (col, d) of chunk (n, blk16, kc): lane = ((d&31)>>3)*16 + (col&15),
// j = d&7, with blk16 = col>>4, kc = d>>5.

typedef __attribute__((ext_vector_type(8))) short bf16x8;   // 8 bf16 = 4 VGPRs
typedef __attribute__((ext_vector_type(4))) float f32x4;

__device__ __forceinline__ ushort f2bf(float x) {           // RNE f32 -> bf16 bits
    uint u = __float_as_uint(x);
    u += 0x7FFFu + ((u >> 16) & 1u);
    return (ushort)(u >> 16);
}
__device__ __forceinline__ float bf2f(ushort h) {
    return __uint_as_float(((uint)h) << 16);
}

typedef const __attribute__((address_space(1))) unsigned int* gptr_t;
typedef __attribute__((address_space(3))) unsigned int* sptr_t;
__device__ __forceinline__ void gload_lds16(const void* g, void* l) {
    __builtin_amdgcn_global_load_lds((gptr_t)g, (sptr_t)l, 16, 0, 0);
}

// ---------------------------------------------------------------------------
// Kernel 0: fp32 -> split bf16 (hi = bf16(v), lo = bf16(v - hi)), elementwise.
// ---------------------------------------------------------------------------
__global__ __launch_bounds__(256)
void convert_split_kernel(const float* __restrict__ in, ushort* __restrict__ hi,
                          ushort* __restrict__ lo, int n4)
{
    int i = blockIdx.x * 256 + threadIdx.x;
    const int stride = gridDim.x * 256;
    for (; i < n4; i += stride) {
        float4 v = ((const float4*)in)[i];
        ushort4 h, l;
        h.x = f2bf(v.x); l.x = f2bf(v.x - bf2f(h.x));
        h.y = f2bf(v.y); l.y = f2bf(v.y - bf2f(h.y));
        h.z = f2bf(v.z); l.z = f2bf(v.z - bf2f(h.z));
        h.w = f2bf(v.w); l.w = f2bf(v.w - bf2f(h.w));
        ((ushort4*)hi)[i] = h;
        ((ushort4*)lo)[i] = l;
    }
}

// ---------------------------------------------------------------------------
// Kernel 1: projection GEMM via split-bf16 MFMA. GEMM core unchanged
// (round 3); epilogue scatters into the fragment-major layout above.
// ---------------------------------------------------------------------------
__global__ __launch_bounds__(512)
void proj_kernel(const ushort* __restrict__ xh, const ushort* __restrict__ xl,
                 const ushort* __restrict__ wh, const ushort* __restrict__ wl,
                 ushort* __restrict__ khi, ushort* __restrict__ klo,
                 ushort* __restrict__ qhi, ushort* __restrict__ qlo)
{
    __shared__ __align__(16) ushort Ah[128 * 64], Al[128 * 64];   // 16 KB each
    __shared__ __align__(16) ushort Bh[128 * 64], Bl[128 * 64];   // total 64 KB
    const int tid = threadIdx.x, w = tid >> 6, l = tid & 63;
    const int m0 = blockIdx.y * 128, c0 = blockIdx.x * 128;
    const int wr = w >> 2, wc = w & 3;          // wave -> 64m x 32c sub-tile
    const int lm = l & 15, lk = l >> 4;
    const int sslot = (l & 7) ^ (l >> 3);       // pre-swizzled source chunk

    f32x4 acc[4][2];
#pragma unroll
    for (int mf = 0; mf < 4; ++mf)
#pragma unroll
        for (int nf = 0; nf < 2; ++nf) acc[mf][nf] = (f32x4){0.f, 0.f, 0.f, 0.f};

    for (int k0 = 0; k0 < 1024; k0 += 64) {
        __syncthreads();                        // prev ds_reads done
#pragma unroll
        for (int i = 0; i < 2; ++i) {
            const int r = 16 * w + 8 * i + (l >> 3);
            const size_t ga = (size_t)(m0 + r) * 1024 + k0 + sslot * 8;
            const size_t gb = (size_t)(c0 + r) * 1024 + k0 + sslot * 8;
            const int lb = (16 * w + 8 * i) * 128;          // LDS byte base (uniform)
            gload_lds16(xh + ga, (char*)Ah + lb);
            gload_lds16(xl + ga, (char*)Al + lb);
            gload_lds16(wh + gb, (char*)Bh + lb);
            gload_lds16(wl + gb, (char*)Bl + lb);
        }
        __syncthreads();                        // vmcnt drained by barrier
#pragma unroll
        for (int kc = 0; kc < 2; ++kc) {
            bf16x8 a_h[4], a_l[4], b_h[2], b_l[2];
#pragma unroll
            for (int mf = 0; mf < 4; ++mf) {
                const int ra = wr * 64 + mf * 16 + lm;
                const int off = ra * 128 + ((kc * 4 + lk) ^ (ra & 7)) * 16;
                a_h[mf] = *(const bf16x8*)((const char*)Ah + off);
                a_l[mf] = *(const bf16x8*)((const char*)Al + off);
            }
#pragma unroll
            for (int nf = 0; nf < 2; ++nf) {
                const int rb = wc * 32 + nf * 16 + lm;
                const int off = rb * 128 + ((kc * 4 + lk) ^ (rb & 7)) * 16;
                b_h[nf] = *(const bf16x8*)((const char*)Bh + off);
                b_l[nf] = *(const bf16x8*)((const char*)Bl + off);
            }
#pragma unroll
            for (int mf = 0; mf < 4; ++mf)
#pragma unroll
                for (int nf = 0; nf < 2; ++nf) {
                    f32x4 a = acc[mf][nf];
                    a = __builtin_amdgcn_mfma_f32_16x16x32_bf16(a_h[mf], b_h[nf], a, 0, 0, 0);
                    a = __builtin_amdgcn_mfma_f32_16x16x32_bf16(a_l[mf], b_h[nf], a, 0, 0, 0);
                    a = __builtin_amdgcn_mfma_f32_16x16x32_bf16(a_h[mf], b_l[nf], a, 0, 0, 0);
                    acc[mf][nf] = a;
                }
        }
    }

    // epilogue: split-bf16, scatter into fragment-major K / Q buffers
#pragma unroll
    for (int mf = 0; mf < 4; ++mf)
#pragma unroll
        for (int nf = 0; nf < 2; ++nf) {
            const int c = c0 + wc * 32 + nf * 16 + lm;
            const int cc = c & 1023;
            ushort* dh = (c < 1024) ? khi : qhi;
            ushort* dl = (c < 1024) ? klo : qlo;
            const int d   = cc & 63;
            const int kc  = d >> 5;             // 32-wide k-half
            const int lkp = (d & 31) >> 3;      // k-slice within half
            const int j   = d & 7;              // elem within lane chunk
#pragma unroll
            for (int rg = 0; rg < 4; ++rg) {
                const int m = m0 + wr * 64 + mf * 16 + lk * 4 + rg;
                const int n = ((m >> 10) << 4) + (cc >> 6);
                const int s = m & 1023;
                const int sblk = s >> 4, lmp = s & 15;
                const size_t off = ((size_t)n << 16)
                                 + ((size_t)((sblk << 1) | kc) << 9)
                                 + (((lkp << 4) + lmp) << 3) + j;
                const float v = acc[mf][nf][rg];
                const ushort h = f2bf(v), lo_ = f2bf(v - bf2f(h));
                dh[off] = h;
                dl[off] = lo_;
            }
        }
}

// ---------------------------------------------------------------------------
// Kernel 2 (round 10): swapped-operand fused logits MFMA + register sparsemax,
// with fragment-major (fully coalesced, 1 KB/instr) K and Q loads.
// 512 threads = 8 waves, 16 q-rows/block, 4096 blocks, XCD-chunked swizzle.
// acc[nf][rg] = logits[q = r0+lm][k = c0 + nf*16 + lk*4 + rg] (HW-verified).
// Partials LDS is [wave][row] (conflict-free); cross-wave combine = 2 DS
// reads + 2 shfl per quantity (lk-split over the 8 wave partials).
// Kept: tau0 = rowmax-1 Michelot, uniform exit, float4 cached stores.
// ---------------------------------------------------------------------------
__global__ __launch_bounds__(512, 6)
void attn_sparsemax_kernel(const ushort* __restrict__ khi, const ushort* __restrict__ klo,
                           const ushort* __restrict__ qhi, const ushort* __restrict__ qlo,
                           float* __restrict__ out)
{
    __shared__ __align__(16) float pm[8][16];        // [wave][row] maxes
    __shared__ __align__(16) float ps[2][8][16];     // ping-pong sums
    __shared__ __align__(16) float pc[2][8][16];     // ping-pong counts
    const int tid = threadIdx.x, wv = tid >> 6, ln = tid & 63;
    const int bid = blockIdx.x;
    const int vb  = (bid & 7) * 512 + (bid >> 3);    // XCD-chunked remap
    const int n   = vb >> 6;                         // head 0..63
    const int r0  = (vb & 63) << 4;                  // q-row base
    const size_t hb = (size_t)n << 16;               // head base, elems
    const int lm = ln & 15, lk = ln >> 4;

    // Q fragments (B operand): chunk (n, r0>>4, kc), lane ln -> 16 B contiguous
    bf16x8 qh[2], ql[2];
    {
        const size_t qb = hb + ((size_t)((r0 >> 4) << 1) << 9) + ((size_t)ln << 3);
        qh[0] = *(const bf16x8*)(qhi + qb);
        qh[1] = *(const bf16x8*)(qhi + qb + 512);
        ql[0] = *(const bf16x8*)(qlo + qb);
        ql[1] = *(const bf16x8*)(qlo + qb + 512);
    }

    f32x4 acc[8];
#pragma unroll
    for (int nf = 0; nf < 8; ++nf) acc[nf] = (f32x4){0.f, 0.f, 0.f, 0.f};

    const int c0 = wv * 128;                         // this wave's 128 k-cols
    // K fragments (A operand): chunks (n, c0/16 + nf, kc)
    const size_t kb = hb + ((size_t)((c0 >> 4) << 1) << 9) + ((size_t)ln << 3);

#pragma unroll
    for (int nf = 0; nf < 8; ++nf) {
        const size_t o = kb + ((size_t)(nf << 1) << 9);
        bf16x8 kh0 = *(const bf16x8*)(khi + o);
        bf16x8 kh1 = *(const bf16x8*)(khi + o + 512);
        bf16x8 kl0 = *(const bf16x8*)(klo + o);
        bf16x8 kl1 = *(const bf16x8*)(klo + o + 512);
        f32x4 a = acc[nf];
        a = __builtin_amdgcn_mfma_f32_16x16x32_bf16(kh0, qh[0], a, 0, 0, 0);
        a = __builtin_amdgcn_mfma_f32_16x16x32_bf16(kh1, qh[1], a, 0, 0, 0);
        a = __builtin_amdgcn_mfma_f32_16x16x32_bf16(kl0, qh[0], a, 0, 0, 0);
        a = __builtin_amdgcn_mfma_f32_16x16x32_bf16(kl1, qh[1], a, 0, 0, 0);
        a = __builtin_amdgcn_mfma_f32_16x16x32_bf16(kh0, ql[0], a, 0, 0, 0);
        a = __builtin_amdgcn_mfma_f32_16x16x32_bf16(kh1, ql[1], a, 0, 0, 0);
        acc[nf] = a;
    }

    // ---- row max: 32 in-lane, 2 shfl hops, cross-wave via pm ----
    {
        float m = acc[0][0];
#pragma unroll
        for (int nf = 0; nf < 8; ++nf)
#pragma unroll
            for (int rg = 0; rg < 4; ++rg) m = fmaxf(m, acc[nf][rg]);
        m = fmaxf(m, __shfl_xor(m, 16));
        m = fmaxf(m, __shfl_xor(m, 32));
        if (ln < 16) pm[wv][ln] = m;
    }
    __syncthreads();

    float tau, kold = 0.f;
    {
        float mx = fmaxf(pm[lk][lm], pm[lk + 4][lm]);   // waves {lk, lk+4}
        mx = fmaxf(mx, __shfl_xor(mx, 16));             // merge lk^1
        mx = fmaxf(mx, __shfl_xor(mx, 32));             // merge lk^2
        tau = mx - 1.0f;
    }

    // ---- Michelot from tau0 = rowmax-1 (support tiny; ~2-3 passes) ----
    int buf = 0;
    for (int it = 0; it < 32; ++it) {
        float sv = 0.f, cv = 0.f;
#pragma unroll
        for (int nf = 0; nf < 8; ++nf)
#pragma unroll
            for (int rg = 0; rg < 4; ++rg) {
                const bool p = acc[nf][rg] > tau;
                sv += p ? acc[nf][rg] : 0.f;
                cv += p ? 1.f : 0.f;
            }
        sv += __shfl_xor(sv, 16); cv += __shfl_xor(cv, 16);
        sv += __shfl_xor(sv, 32); cv += __shfl_xor(cv, 32);
        if (ln < 16) { ps[buf][wv][ln] = sv; pc[buf][wv][ln] = cv; }
        __syncthreads();
        float S = ps[buf][lk][lm] + ps[buf][lk + 4][lm];
        float C = pc[buf][lk][lm] + pc[buf][lk + 4][lm];
        S += __shfl_xor(S, 16); C += __shfl_xor(C, 16);
        S += __shfl_xor(S, 32); C += __shfl_xor(C, 32);
        const bool st = (C == kold);
        kold = C;
        tau = (S - 1.0f) / C;      // bit-identical when row converged
        buf ^= 1;
        if (__all(st)) break;      // identical totals everywhere -> uniform exit
    }

    // ---- fused relu write: native float4 per accumulator, cached stores ----
    float* orow = out + ((((size_t)n << 10) + r0 + lm) << 10) + c0 + (lk << 2);
#pragma unroll
    for (int nf = 0; nf < 8; ++nf) {
        f32x4 o;
        o[0] = fmaxf(acc[nf][0] - tau, 0.f);
        o[1] = fmaxf(acc[nf][1] - tau, 0.f);
        o[2] = fmaxf(acc[nf][2] - tau, 0.f);
        o[3] = fmaxf(acc[nf][3] - tau, 0.f);
        *(f32x4*)(orow + nf * 16) = o;
    }
}

// ---------------------------------------------------------------------------
extern "C" void kernel_launch(void* const* d_in, const int* in_sizes, int n_in,
                              void* d_out, int out_size, void* d_ws, size_t ws_size,
                              hipStream_t stream) {
    const float* x = (const float*)d_in[0];          // [4096, 1024]
    const float* w = (const float*)d_in[1];          // [3072, 1024]
    float* out = (float*)d_out;                      // [64, 1024, 1024]

    const size_t HE = (size_t)64 * 1024 * 64;        // 4.19M elems per head buf
    const size_t XE = (size_t)4096 * 1024;           // x elems
    const size_t WE = (size_t)2048 * 1024;           // W' elems (rows 1024..3071)
    ushort* khi = (ushort*)d_ws;
    ushort* klo = khi + HE;
    ushort* qhi = klo + HE;
    ushort* qlo = qhi + HE;
    ushort* xh  = qlo + HE;
    ushort* xl  = xh + XE;
    ushort* wh  = xl + XE;
    ushort* wl  = wh + WE;                           // total ~58.7 MB of d_ws

    convert_split_kernel<<<2048, 256, 0, stream>>>(x, xh, xl, (int)(XE / 4));
    convert_split_kernel<<<2048, 256, 0, stream>>>(w + (size_t)1024 * 1024, wh, wl, (int)(WE / 4));
    proj_kernel<<<dim3(16, 32), 512, 0, stream>>>(xh, xl, wh, wl, khi, klo, qhi, qlo);
    attn_sparsemax_kernel<<<4096, 512, 0, stream>>>(khi, klo, qhi, qlo, out);
}